// Round 3
// baseline (530.059 us; speedup 1.0000x reference)
//
#include <hip/hip_runtime.h>
#include <hip/hip_bf16.h>

// Problem constants
#define BB 4
#define SS 12
#define NN 307
#define LL 1228      // B*N
#define BSC 48       // B*S
#define GG 48        // S*HEADS
// Workspace offsets (floats)
#define WS_CX    0           // [3][3][48][307] = 132624
#define WS_CROW  132624      // [3][307]
#define WS_TXD   133568      // [3][64]
#define WS_TBD   133760
#define WS_T1D   133952
#define WS_T2D   134144
#define WS_TOB   134336
#define WS_WRCT  134528      // [64][64] W_rc transposed
#define WS_WOT   138624      // [64][64] W_out transposed
#define WS_H2    142720      // [B][S][N][64] post-FF hidden = 943104
#define WS_TFL   1085824     // [B][64][307] tc_last in (b,f,n) order = 78592
#define WS_XFL   1164416     // [B][S][64][307] emb_x in (b,s,e,n) order = 943104
#define WS_QH    2107520     // [48][1228][16]
#define WS_KH    3050624
#define WS_VH    3993728
#define WS_CTX   4936832     // [1228][12][64]  (ends 5879936 floats = 23.5 MB)

// ---------------- K1: tiny weight precomputations (1 block) ----------------
__global__ __launch_bounds__(256) void k1_precomp(
    const float* __restrict__ theta, const float* __restrict__ Wex,
    const float* __restrict__ bex, const float* __restrict__ Weos,
    const float* __restrict__ beos, const float* __restrict__ W_rc,
    const float* __restrict__ W_out, float* __restrict__ ws) {
  int tid = threadIdx.x;
  if (tid < 192) {
    int k = tid / 64, d = tid % 64;
    float a0 = 0.f, a1 = 0.f, a2 = 0.f, a3 = 0.f, a4 = 0.f;
    for (int c = 0; c < 64; ++c) {
      float th = theta[(k * 64 + c) * 64 + d];
      a0 = fmaf(Wex[c], th, a0);
      a1 = fmaf(bex[c], th, a1);
      a2 = fmaf(Weos[c], th, a2);
      a3 = fmaf(Weos[64 + c], th, a3);
      a4 = fmaf(beos[c], th, a4);
    }
    ws[WS_TXD + tid] = a0; ws[WS_TBD + tid] = a1; ws[WS_T1D + tid] = a2;
    ws[WS_T2D + tid] = a3; ws[WS_TOB + tid] = a4;
  }
  for (int i = tid; i < 4096; i += 256) {
    int hh = i >> 6, f = i & 63;
    ws[WS_WRCT + i] = W_rc[f * 64 + hh];   // WrcT[h][f] = W_rc[f][h]
    ws[WS_WOT + i]  = W_out[f * 64 + hh];  // WoT[f'][f] = W_out[f][f']
  }
}

// ---------------- K2: cheb projections of raw x channels -------------------
__global__ __launch_bounds__(320) void k2_cx(const float* __restrict__ x,
                                             const float* __restrict__ cheb,
                                             float* __restrict__ ws) {
  int k = blockIdx.x / BSC, bs = blockIdx.x % BSC;
  __shared__ float xl[921];
  for (int i = threadIdx.x; i < 921; i += 320) xl[i] = x[bs * 921 + i];
  __syncthreads();
  int m = threadIdx.x;
  if (m < NN) {
    const float* ch = cheb + (k * NN + m) * NN;
    float a0 = 0.f, a1 = 0.f, a2 = 0.f, ar = 0.f;
    for (int n = 0; n < NN; ++n) {
      float c = ch[n];
      ar += c;
      a0 = fmaf(c, xl[3 * n], a0);
      a1 = fmaf(c, xl[3 * n + 1], a1);
      a2 = fmaf(c, xl[3 * n + 2], a2);
    }
    ws[WS_CX + ((k * 3 + 0) * BSC + bs) * NN + m] = a0;
    ws[WS_CX + ((k * 3 + 1) * BSC + bs) * NN + m] = a1;
    ws[WS_CX + ((k * 3 + 2) * BSC + bs) * NN + m] = a2;
    if (bs == 0) ws[WS_CROW + k * NN + m] = ar;
  }
}

// ---------------- K2c: materialize emb_x in (b,s,e,n) order ----------------
__global__ __launch_bounds__(256) void k2c_xfl(const float* __restrict__ x,
                                               const float* __restrict__ Wex,
                                               const float* __restrict__ bex,
                                               float* __restrict__ ws) {
  int idx = blockIdx.x * 256 + threadIdx.x;
  if (idx < 943104) {
    int n = idx % NN;
    int t = idx / NN;
    int e = t & 63;
    int bs = t >> 6;
    ws[WS_XFL + idx] = fmaf(x[(bs * NN + n) * 3], Wex[e], bex[e]);
  }
}

// ---- K3: fused gcn + U-projection + 12-step LSTM scan + FF + tc_last ------
__global__ __launch_bounds__(384) void k3_scan(
    const float* __restrict__ U_x, const float* __restrict__ V_x,
    const float* __restrict__ b_x, const float* __restrict__ U_g,
    const float* __restrict__ V_g, const float* __restrict__ b_g,
    const float* __restrict__ W_ff1, const float* __restrict__ b_ff1,
    const float* __restrict__ W_ff2, const float* __restrict__ b_ff2,
    const float* __restrict__ W_tc, const float* __restrict__ b_tc,
    float* __restrict__ ws) {
  int l = blockIdx.x;
  int b = l / NN, n = l % NN;
  int tid = threadIdx.x;
  __shared__ float gcx[768], gcos[768], hsb[768], sg[256], sv[128];

  // Phase A: gcn_x / gcn_os rows for all 12 timesteps
  for (int idx = tid; idx < 768; idx += 384) {
    int s = idx >> 6, d = idx & 63;
    int bs = b * SS + s;
    float ax = 0.f, ao = 0.f;
#pragma unroll
    for (int k = 0; k < 3; ++k) {
      float c0 = ws[WS_CX + ((k * 3 + 0) * BSC + bs) * NN + n];
      float c1 = ws[WS_CX + ((k * 3 + 1) * BSC + bs) * NN + n];
      float c2 = ws[WS_CX + ((k * 3 + 2) * BSC + bs) * NN + n];
      float cr = ws[WS_CROW + k * NN + n];
      ax += c0 * ws[WS_TXD + k * 64 + d] + cr * ws[WS_TBD + k * 64 + d];
      ao += c1 * ws[WS_T1D + k * 64 + d] + c2 * ws[WS_T2D + k * 64 + d] +
            cr * ws[WS_TOB + k * 64 + d];
    }
    gcx[idx] = fmaxf(ax, 0.f);
    gcos[idx] = fmaxf(ao, 0.f);
  }
  __syncthreads();

  // Phase B: input projections (gx/gg) into registers + V columns into regs
  float gr[12];
  float vcol[64];
  if (tid < 256) {
#pragma unroll
    for (int s = 0; s < 12; ++s) gr[s] = b_x[tid];
    for (int c = 0; c < 64; ++c) {
      float u = U_x[c * 256 + tid];
#pragma unroll
      for (int s = 0; s < 12; ++s) gr[s] = fmaf(gcx[s * 64 + c], u, gr[s]);
    }
#pragma unroll
    for (int c = 0; c < 64; ++c) vcol[c] = V_x[c * 256 + tid];
  } else {
    int j = tid - 256;
#pragma unroll
    for (int s = 0; s < 12; ++s) gr[s] = b_g[j];
    for (int c = 0; c < 64; ++c) {
      float u = U_g[c * 128 + j];
#pragma unroll
      for (int s = 0; s < 12; ++s) gr[s] = fmaf(gcos[s * 64 + c], u, gr[s]);
    }
#pragma unroll
    for (int c = 0; c < 64; ++c) vcol[c] = V_g[c * 128 + j];
  }

  // Scan: 12 sequential steps, all in-block
  float ct = 0.f;
  for (int s = 0; s < 12; ++s) {
    float a = gr[s];
    if (s > 0) {
      const float* hp = &hsb[(s - 1) * 64];
#pragma unroll
      for (int h = 0; h < 64; ++h) a = fmaf(hp[h], vcol[h], a);
    }
    float sig = 1.f / (1.f + __expf(-a));
    if (tid < 256) sg[tid] = sig; else sv[tid - 256] = sig;
    __syncthreads();
    if (tid < 64) {
      // ft=sg[0:64] it=sg[64:128] ot=sg[128:192] ut=sg[192:256]; gf=sv[0:64] gu=sv[64:128]
      ct = sv[tid] * sg[tid] * ct + sv[64 + tid] * sg[64 + tid] * sg[192 + tid];
      hsb[s * 64 + tid] = sg[128 + tid] * tanhf(ct);
    }
    __syncthreads();
  }

  // FF part 1: t = relu(hs @ W_ff1 + b_ff1)  (reuse gcx)
  for (int idx = tid; idx < 768; idx += 384) {
    int s = idx >> 6, d = idx & 63;
    float a = b_ff1[d];
    for (int c = 0; c < 64; ++c) a = fmaf(hsb[s * 64 + c], W_ff1[c * 64 + d], a);
    gcx[idx] = fmaxf(a, 0.f);
  }
  __syncthreads();
  // FF part 2: h2 = t @ W_ff2 + b_ff2 -> global + LDS (reuse gcos)
  for (int idx = tid; idx < 768; idx += 384) {
    int s = idx >> 6, h = idx & 63;
    float a = b_ff2[h];
    for (int d = 0; d < 64; ++d) a = fmaf(gcx[s * 64 + d], W_ff2[d * 64 + h], a);
    ws[WS_H2 + ((b * SS + s) * NN + n) * 64 + h] = a;
    gcos[idx] = a;
  }
  __syncthreads();
  // tc_last: 2-tap time conv at s = S-1, stored (b,f,n)
  if (tid < 64) {
    int f = tid;
    float a = b_tc[f];
    for (int h = 0; h < 64; ++h) {
      a = fmaf(gcos[10 * 64 + h], W_tc[(f * 64 + h) * 3 + 0], a);
      a = fmaf(gcos[11 * 64 + h], W_tc[(f * 64 + h) * 3 + 1], a);
    }
    ws[WS_TFL + (b * 64 + f) * NN + n] = a;
  }
}

// ---------------- K5: q/k/v projections from flat windows ------------------
__global__ __launch_bounds__(256) void k5_qkv(const float* __restrict__ W_in,
                                              const float* __restrict__ b_in,
                                              float* __restrict__ ws) {
  int blk = blockIdx.x;
  int g = blk / 77, mt = blk % 77;
  int s = g >> 2, a = g & 3;
  int m0 = mt * 16;
  __shared__ float xw[16][64], qw[16][64];
  for (int i = threadIdx.x; i < 1024; i += 256) {
    int mi = i >> 6, e = i & 63;
    int m = m0 + mi;
    if (m < LL) {
      int base = m * 768 + s * 64;         // 64-aligned; never straddles (b,s) runs
      xw[mi][e] = ws[WS_XFL + base + e];
      int bq = base / 235776;              // 235776 = S*64*307
      int off = base % 19648;              // 19648 = 64*307
      qw[mi][e] = ws[WS_TFL + bq * 19648 + off + e];
    }
  }
  __syncthreads();
  int mi = threadIdx.x >> 4, d = threadIdx.x & 15;
  int m = m0 + mi;
  if (m < LL) {
    int f = a * 16 + d;
    float aq = b_in[f], ak = b_in[64 + f], av = b_in[128 + f];
    for (int e = 0; e < 64; ++e) {
      aq = fmaf(qw[mi][e], W_in[f * 64 + e], aq);
      ak = fmaf(xw[mi][e], W_in[(64 + f) * 64 + e], ak);
      av = fmaf(xw[mi][e], W_in[(128 + f) * 64 + e], av);
    }
    int o = (g * LL + m) * 16 + d;
    ws[WS_QH + o] = aq; ws[WS_KH + o] = ak; ws[WS_VH + o] = av;
  }
}

// ---------------- K6: flash attention (hd=16, L=1228, G=48) ----------------
__global__ __launch_bounds__(256) void k6_attn(float* __restrict__ ws) {
  int blk = blockIdx.x;
  int g = blk / 5, lt = blk % 5;
  int s = g >> 2, a = g & 3;
  int l = lt * 256 + threadIdx.x;
  __shared__ float kl[256][16], vl[256][16];
  float q[16], cx[16];
  float mx = -1e30f, den = 0.f;
  bool act = (l < LL);
  if (act) {
    const float* qp = ws + WS_QH + (g * LL + l) * 16;
#pragma unroll
    for (int d = 0; d < 16; ++d) { q[d] = qp[d]; cx[d] = 0.f; }
  }
  for (int mt = 0; mt < 5; ++mt) {
    int mbase = mt * 256;
    int cnt = LL - mbase; if (cnt > 256) cnt = 256;
    for (int i = threadIdx.x; i < cnt * 16; i += 256) {
      int mi = i >> 4, d = i & 15;
      kl[mi][d] = ws[WS_KH + (g * LL + mbase + mi) * 16 + d];
      vl[mi][d] = ws[WS_VH + (g * LL + mbase + mi) * 16 + d];
    }
    __syncthreads();
    if (act) {
      for (int mi = 0; mi < cnt; ++mi) {
        float sc = 0.f;
#pragma unroll
        for (int d = 0; d < 16; ++d) sc = fmaf(q[d], kl[mi][d], sc);
        sc *= 0.25f;  // / sqrt(16)
        if (sc > mx) {
          float r = __expf(mx - sc);
          den *= r;
#pragma unroll
          for (int d = 0; d < 16; ++d) cx[d] *= r;
          mx = sc;
        }
        float w = __expf(sc - mx);
        den += w;
#pragma unroll
        for (int d = 0; d < 16; ++d) cx[d] = fmaf(w, vl[mi][d], cx[d]);
      }
    }
    __syncthreads();
  }
  if (act) {
    float inv = 1.f / den;
    float* cp = ws + WS_CTX + (l * SS + s) * 64 + a * 16;
#pragma unroll
    for (int d = 0; d < 16; ++d) cp[d] = cx[d] * inv;
  }
}

// ---------------- K7: out-proj + FFA + residual conv + final conv ----------
__global__ __launch_bounds__(64) void k7_out(
    const float* __restrict__ W_fa1, const float* __restrict__ b_fa1,
    const float* __restrict__ W_fa2, const float* __restrict__ b_fa2,
    const float* __restrict__ b_rc, const float* __restrict__ b_out,
    const float* __restrict__ W_fin, const float* __restrict__ b_fin,
    const float* __restrict__ ws, float* __restrict__ out) {
  int l = blockIdx.x, b = l / NN, n = l % NN;
  int f = threadIdx.x;
  __shared__ float h2r[64], ctr[64], dsr[64], tr[64], comb[768];
  for (int s = 0; s < 12; ++s) {
    h2r[f] = ws[WS_H2 + ((b * SS + s) * NN + n) * 64 + f];
    ctr[f] = ws[WS_CTX + (l * SS + s) * 64 + f];
    __syncthreads();
    float a = b_out[f];
    for (int q = 0; q < 64; ++q) a = fmaf(ctr[q], ws[WS_WOT + q * 64 + f], a);
    dsr[f] = a;
    __syncthreads();
    float t = b_fa1[f];
    for (int q = 0; q < 64; ++q) t = fmaf(dsr[q], W_fa1[q * 64 + f], t);
    tr[f] = fmaxf(t, 0.f);
    float r = b_rc[f];
    for (int q = 0; q < 64; ++q) r = fmaf(h2r[q], ws[WS_WRCT + q * 64 + f], r);
    __syncthreads();
    float ff = b_fa2[f];
    for (int q = 0; q < 64; ++q) ff = fmaf(tr[q], W_fa2[q * 64 + f], ff);
    comb[s * 64 + f] = r + ff;
    __syncthreads();
  }
  if (f < 12) {
    float o = b_fin[f];
    for (int i = 0; i < 768; ++i) {
      int s = i >> 6, q = i & 63;
      o = fmaf(comb[i], W_fin[(f * SS + s) * 64 + q], o);
    }
    out[(b * SS + f) * NN + n] = o;
  }
}

extern "C" void kernel_launch(void* const* d_in, const int* in_sizes, int n_in,
                              void* d_out, int out_size, void* d_ws, size_t ws_size,
                              hipStream_t stream) {
  (void)in_sizes; (void)n_in; (void)out_size; (void)ws_size;
  const float* x     = (const float*)d_in[0];
  const float* cheb  = (const float*)d_in[1];
  const float* theta = (const float*)d_in[2];
  const float* Wex   = (const float*)d_in[3];
  const float* bex   = (const float*)d_in[4];
  const float* Weos  = (const float*)d_in[5];
  const float* beos  = (const float*)d_in[6];
  const float* U_x   = (const float*)d_in[7];
  const float* V_x   = (const float*)d_in[8];
  const float* b_x   = (const float*)d_in[9];
  const float* U_g   = (const float*)d_in[10];
  const float* V_g   = (const float*)d_in[11];
  const float* b_g   = (const float*)d_in[12];
  const float* W_ff1 = (const float*)d_in[13];
  const float* b_ff1 = (const float*)d_in[14];
  const float* W_ff2 = (const float*)d_in[15];
  const float* b_ff2 = (const float*)d_in[16];
  const float* W_tc  = (const float*)d_in[17];
  const float* b_tc  = (const float*)d_in[18];
  const float* W_rc  = (const float*)d_in[19];
  const float* b_rc  = (const float*)d_in[20];
  const float* W_in  = (const float*)d_in[21];
  const float* b_in  = (const float*)d_in[22];
  const float* W_out = (const float*)d_in[23];
  const float* b_out = (const float*)d_in[24];
  const float* W_fa1 = (const float*)d_in[25];
  const float* b_fa1 = (const float*)d_in[26];
  const float* W_fa2 = (const float*)d_in[27];
  const float* b_fa2 = (const float*)d_in[28];
  const float* W_fin = (const float*)d_in[29];
  const float* b_fin = (const float*)d_in[30];
  float* ws = (float*)d_ws;
  float* outp = (float*)d_out;

  k1_precomp<<<1, 256, 0, stream>>>(theta, Wex, bex, Weos, beos, W_rc, W_out, ws);
  k2_cx<<<144, 320, 0, stream>>>(x, cheb, ws);
  k2c_xfl<<<3684, 256, 0, stream>>>(x, Wex, bex, ws);
  k3_scan<<<1228, 384, 0, stream>>>(U_x, V_x, b_x, U_g, V_g, b_g,
                                    W_ff1, b_ff1, W_ff2, b_ff2, W_tc, b_tc, ws);
  k5_qkv<<<48 * 77, 256, 0, stream>>>(W_in, b_in, ws);
  k6_attn<<<240, 256, 0, stream>>>(ws);
  k7_out<<<1228, 64, 0, stream>>>(W_fa1, b_fa1, W_fa2, b_fa2, b_rc, b_out,
                                  W_fin, b_fin, ws, outp);
}

// Round 4
// 527.948 us; speedup vs baseline: 1.0040x; 1.0040x over previous
//
#include <hip/hip_runtime.h>
#include <hip/hip_bf16.h>

// Problem constants
#define BB 4
#define SS 12
#define NN 307
#define LL 1228      // B*N
#define BSC 48       // B*S
#define GG 48        // S*HEADS
// Workspace offsets (floats)
#define WS_CX    0           // [3][3][48][307] = 132624
#define WS_CROW  132624      // [3][307]
#define WS_TXD   133568      // [3][64]
#define WS_TBD   133760
#define WS_T1D   133952
#define WS_T2D   134144
#define WS_TOB   134336
#define WS_WRCT  134528      // [64][64] W_rc transposed
#define WS_WOT   138624      // [64][64] W_out transposed
#define WS_H2    142720      // [B][S][N][64] post-FF hidden = 943104
#define WS_TFL   1085824     // [B][64][307] tc_last in (b,f,n) order = 78592
#define WS_XFL   1164416     // [B][S][64][307] emb_x in (b,s,e,n) order = 943104
#define WS_QH    2107520     // [48][1228][16]
#define WS_KH    3050624
#define WS_VH    3993728
#define WS_CTX   4936832     // [1228][12][64]  (ends 5879936 floats = 23.5 MB)

// ---------------- K1: tiny weight precomputations (1 block) ----------------
__global__ __launch_bounds__(256) void k1_precomp(
    const float* __restrict__ theta, const float* __restrict__ Wex,
    const float* __restrict__ bex, const float* __restrict__ Weos,
    const float* __restrict__ beos, const float* __restrict__ W_rc,
    const float* __restrict__ W_out, float* __restrict__ ws) {
  int tid = threadIdx.x;
  if (tid < 192) {
    int k = tid / 64, d = tid % 64;
    float a0 = 0.f, a1 = 0.f, a2 = 0.f, a3 = 0.f, a4 = 0.f;
    for (int c = 0; c < 64; ++c) {
      float th = theta[(k * 64 + c) * 64 + d];
      a0 = fmaf(Wex[c], th, a0);
      a1 = fmaf(bex[c], th, a1);
      a2 = fmaf(Weos[c], th, a2);
      a3 = fmaf(Weos[64 + c], th, a3);
      a4 = fmaf(beos[c], th, a4);
    }
    ws[WS_TXD + tid] = a0; ws[WS_TBD + tid] = a1; ws[WS_T1D + tid] = a2;
    ws[WS_T2D + tid] = a3; ws[WS_TOB + tid] = a4;
  }
  for (int i = tid; i < 4096; i += 256) {
    int hh = i >> 6, f = i & 63;
    ws[WS_WRCT + i] = W_rc[f * 64 + hh];   // WrcT[h][f] = W_rc[f][h]
    ws[WS_WOT + i]  = W_out[f * 64 + hh];  // WoT[f'][f] = W_out[f][f']
  }
}

// ---------------- K2: cheb projections of raw x channels -------------------
__global__ __launch_bounds__(320) void k2_cx(const float* __restrict__ x,
                                             const float* __restrict__ cheb,
                                             float* __restrict__ ws) {
  int k = blockIdx.x / BSC, bs = blockIdx.x % BSC;
  __shared__ float xl[921];
  for (int i = threadIdx.x; i < 921; i += 320) xl[i] = x[bs * 921 + i];
  __syncthreads();
  int m = threadIdx.x;
  if (m < NN) {
    const float* ch = cheb + (k * NN + m) * NN;
    float a0 = 0.f, a1 = 0.f, a2 = 0.f, ar = 0.f;
    for (int n = 0; n < NN; ++n) {
      float c = ch[n];
      ar += c;
      a0 = fmaf(c, xl[3 * n], a0);
      a1 = fmaf(c, xl[3 * n + 1], a1);
      a2 = fmaf(c, xl[3 * n + 2], a2);
    }
    ws[WS_CX + ((k * 3 + 0) * BSC + bs) * NN + m] = a0;
    ws[WS_CX + ((k * 3 + 1) * BSC + bs) * NN + m] = a1;
    ws[WS_CX + ((k * 3 + 2) * BSC + bs) * NN + m] = a2;
    if (bs == 0) ws[WS_CROW + k * NN + m] = ar;
  }
}

// ---------------- K2c: materialize emb_x in (b,s,e,n) order ----------------
__global__ __launch_bounds__(256) void k2c_xfl(const float* __restrict__ x,
                                               const float* __restrict__ Wex,
                                               const float* __restrict__ bex,
                                               float* __restrict__ ws) {
  int idx = blockIdx.x * 256 + threadIdx.x;
  if (idx < 943104) {
    int n = idx % NN;
    int t = idx / NN;
    int e = t & 63;
    int bs = t >> 6;
    ws[WS_XFL + idx] = fmaf(x[(bs * NN + n) * 3], Wex[e], bex[e]);
  }
}

// ---- K3: fused gcn + U-projection + 12-step LSTM scan + FF + tc_last ------
__global__ __launch_bounds__(384) void k3_scan(
    const float* __restrict__ U_x, const float* __restrict__ V_x,
    const float* __restrict__ b_x, const float* __restrict__ U_g,
    const float* __restrict__ V_g, const float* __restrict__ b_g,
    const float* __restrict__ W_ff1, const float* __restrict__ b_ff1,
    const float* __restrict__ W_ff2, const float* __restrict__ b_ff2,
    const float* __restrict__ W_tc, const float* __restrict__ b_tc,
    float* __restrict__ ws) {
  int l = blockIdx.x;
  int b = l / NN, n = l % NN;
  int tid = threadIdx.x;
  __shared__ float gcx[768], gcos[768], hsb[768], sg[256], sv[128];

  // Phase A: gcn_x / gcn_os rows for all 12 timesteps
  for (int idx = tid; idx < 768; idx += 384) {
    int s = idx >> 6, d = idx & 63;
    int bs = b * SS + s;
    float ax = 0.f, ao = 0.f;
#pragma unroll
    for (int k = 0; k < 3; ++k) {
      float c0 = ws[WS_CX + ((k * 3 + 0) * BSC + bs) * NN + n];
      float c1 = ws[WS_CX + ((k * 3 + 1) * BSC + bs) * NN + n];
      float c2 = ws[WS_CX + ((k * 3 + 2) * BSC + bs) * NN + n];
      float cr = ws[WS_CROW + k * NN + n];
      ax += c0 * ws[WS_TXD + k * 64 + d] + cr * ws[WS_TBD + k * 64 + d];
      ao += c1 * ws[WS_T1D + k * 64 + d] + c2 * ws[WS_T2D + k * 64 + d] +
            cr * ws[WS_TOB + k * 64 + d];
    }
    gcx[idx] = fmaxf(ax, 0.f);
    gcos[idx] = fmaxf(ao, 0.f);
  }
  __syncthreads();

  // Phase B: input projections (gx/gg) into registers + V columns into regs
  float gr[12];
  float vcol[64];
  if (tid < 256) {
#pragma unroll
    for (int s = 0; s < 12; ++s) gr[s] = b_x[tid];
    for (int c = 0; c < 64; ++c) {
      float u = U_x[c * 256 + tid];
#pragma unroll
      for (int s = 0; s < 12; ++s) gr[s] = fmaf(gcx[s * 64 + c], u, gr[s]);
    }
#pragma unroll
    for (int c = 0; c < 64; ++c) vcol[c] = V_x[c * 256 + tid];
  } else {
    int j = tid - 256;
#pragma unroll
    for (int s = 0; s < 12; ++s) gr[s] = b_g[j];
    for (int c = 0; c < 64; ++c) {
      float u = U_g[c * 128 + j];
#pragma unroll
      for (int s = 0; s < 12; ++s) gr[s] = fmaf(gcos[s * 64 + c], u, gr[s]);
    }
#pragma unroll
    for (int c = 0; c < 64; ++c) vcol[c] = V_g[c * 128 + j];
  }

  // Scan: 12 sequential steps, all in-block
  float ct = 0.f;
  for (int s = 0; s < 12; ++s) {
    float a = gr[s];
    if (s > 0) {
      const float* hp = &hsb[(s - 1) * 64];
#pragma unroll
      for (int h = 0; h < 64; ++h) a = fmaf(hp[h], vcol[h], a);
    }
    float sig = 1.f / (1.f + __expf(-a));
    if (tid < 256) sg[tid] = sig; else sv[tid - 256] = sig;
    __syncthreads();
    if (tid < 64) {
      // ft=sg[0:64] it=sg[64:128] ot=sg[128:192] ut=sg[192:256]; gf=sv[0:64] gu=sv[64:128]
      ct = sv[tid] * sg[tid] * ct + sv[64 + tid] * sg[64 + tid] * sg[192 + tid];
      hsb[s * 64 + tid] = sg[128 + tid] * tanhf(ct);
    }
    __syncthreads();
  }

  // FF part 1: t = relu(hs @ W_ff1 + b_ff1)  (reuse gcx)
  for (int idx = tid; idx < 768; idx += 384) {
    int s = idx >> 6, d = idx & 63;
    float a = b_ff1[d];
    for (int c = 0; c < 64; ++c) a = fmaf(hsb[s * 64 + c], W_ff1[c * 64 + d], a);
    gcx[idx] = fmaxf(a, 0.f);
  }
  __syncthreads();
  // FF part 2: h2 = t @ W_ff2 + b_ff2 -> global + LDS (reuse gcos)
  for (int idx = tid; idx < 768; idx += 384) {
    int s = idx >> 6, h = idx & 63;
    float a = b_ff2[h];
    for (int d = 0; d < 64; ++d) a = fmaf(gcx[s * 64 + d], W_ff2[d * 64 + h], a);
    ws[WS_H2 + ((b * SS + s) * NN + n) * 64 + h] = a;
    gcos[idx] = a;
  }
  __syncthreads();
  // tc_last: 2-tap time conv at s = S-1, stored (b,f,n)
  if (tid < 64) {
    int f = tid;
    float a = b_tc[f];
    for (int h = 0; h < 64; ++h) {
      a = fmaf(gcos[10 * 64 + h], W_tc[(f * 64 + h) * 3 + 0], a);
      a = fmaf(gcos[11 * 64 + h], W_tc[(f * 64 + h) * 3 + 1], a);
    }
    ws[WS_TFL + (b * 64 + f) * NN + n] = a;
  }
}

// ---------------- K5: q/k/v projections from flat windows ------------------
__global__ __launch_bounds__(256) void k5_qkv(const float* __restrict__ W_in,
                                              const float* __restrict__ b_in,
                                              float* __restrict__ ws) {
  int blk = blockIdx.x;
  int g = blk / 77, mt = blk % 77;
  int s = g >> 2, a = g & 3;
  int m0 = mt * 16;
  __shared__ float xw[16][64], qw[16][64];
  for (int i = threadIdx.x; i < 1024; i += 256) {
    int mi = i >> 6, e = i & 63;
    int m = m0 + mi;
    if (m < LL) {
      int base = m * 768 + s * 64;         // 64-aligned; never straddles (b,s) runs
      xw[mi][e] = ws[WS_XFL + base + e];
      int bq = base / 235776;              // 235776 = S*64*307
      int off = base % 19648;              // 19648 = 64*307
      qw[mi][e] = ws[WS_TFL + bq * 19648 + off + e];
    }
  }
  __syncthreads();
  int mi = threadIdx.x >> 4, d = threadIdx.x & 15;
  int m = m0 + mi;
  if (m < LL) {
    int f = a * 16 + d;
    float aq = b_in[f], ak = b_in[64 + f], av = b_in[128 + f];
    for (int e = 0; e < 64; ++e) {
      aq = fmaf(qw[mi][e], W_in[f * 64 + e], aq);
      ak = fmaf(xw[mi][e], W_in[(64 + f) * 64 + e], ak);
      av = fmaf(xw[mi][e], W_in[(128 + f) * 64 + e], av);
    }
    int o = (g * LL + m) * 16 + d;
    ws[WS_QH + o] = aq; ws[WS_KH + o] = ak; ws[WS_VH + o] = av;
  }
}

// ------- K6: flash attention, quad-cooperative (4 lanes per query) ---------
// grid = 48 groups x 20 query-tiles of 64; block = 256 threads.
// tid -> qi = tid>>2 (query in tile), j = tid&3 (4-dim slice of hd=16).
__global__ __launch_bounds__(256) void k6_attn(float* __restrict__ ws) {
  int blk = blockIdx.x;
  int g = blk / 20, qt = blk % 20;
  int s = g >> 2, a = g & 3;
  int tid = threadIdx.x;
  int qi = tid >> 2, j = tid & 3;
  int l = qt * 64 + qi;
  bool act = (l < LL);

  __shared__ float4 kl4[256][4], vl4[256][4];

  float4 q4 = make_float4(0.f, 0.f, 0.f, 0.f);
  if (act) {
    float4 t = *reinterpret_cast<const float4*>(ws + WS_QH + (g * LL + l) * 16 + j * 4);
    q4 = make_float4(t.x * 0.25f, t.y * 0.25f, t.z * 0.25f, t.w * 0.25f);
  }
  float4 cx = make_float4(0.f, 0.f, 0.f, 0.f);
  float mx = -1e30f, den = 0.f;

  for (int mt = 0; mt < 5; ++mt) {
    int mbase = mt * 256;
    int cnt = LL - mbase; if (cnt > 256) cnt = 256;
    for (int i = tid; i < cnt * 4; i += 256) {
      int mi = i >> 2, jj = i & 3;
      kl4[mi][jj] = *reinterpret_cast<const float4*>(
          ws + WS_KH + (g * LL + mbase + mi) * 16 + jj * 4);
      vl4[mi][jj] = *reinterpret_cast<const float4*>(
          ws + WS_VH + (g * LL + mbase + mi) * 16 + jj * 4);
    }
    __syncthreads();
#pragma unroll 2
    for (int mi = 0; mi < cnt; ++mi) {
      float4 k4 = kl4[mi][j];
      float p = q4.x * k4.x;
      p = fmaf(q4.y, k4.y, p);
      p = fmaf(q4.z, k4.z, p);
      p = fmaf(q4.w, k4.w, p);
      p += __shfl_xor(p, 1, 64);
      p += __shfl_xor(p, 2, 64);        // full (pre-scaled) score in all 4 lanes
      if (p > mx) {
        float r = __expf(mx - p);
        den *= r;
        cx.x *= r; cx.y *= r; cx.z *= r; cx.w *= r;
        mx = p;
      }
      float w = __expf(p - mx);
      den += w;
      float4 v4 = vl4[mi][j];
      cx.x = fmaf(w, v4.x, cx.x);
      cx.y = fmaf(w, v4.y, cx.y);
      cx.z = fmaf(w, v4.z, cx.z);
      cx.w = fmaf(w, v4.w, cx.w);
    }
    __syncthreads();
  }
  if (act) {
    float inv = 1.f / den;
    float* cp = ws + WS_CTX + (l * SS + s) * 64 + a * 16 + j * 4;
    *reinterpret_cast<float4*>(cp) =
        make_float4(cx.x * inv, cx.y * inv, cx.z * inv, cx.w * inv);
  }
}

// ---------------- K7: out-proj + FFA + residual conv + final conv ----------
__global__ __launch_bounds__(64) void k7_out(
    const float* __restrict__ W_fa1, const float* __restrict__ b_fa1,
    const float* __restrict__ W_fa2, const float* __restrict__ b_fa2,
    const float* __restrict__ b_rc, const float* __restrict__ b_out,
    const float* __restrict__ W_fin, const float* __restrict__ b_fin,
    const float* __restrict__ ws, float* __restrict__ out) {
  int l = blockIdx.x, b = l / NN, n = l % NN;
  int f = threadIdx.x;
  __shared__ float h2r[64], ctr[64], dsr[64], tr[64], comb[768];
  for (int s = 0; s < 12; ++s) {
    h2r[f] = ws[WS_H2 + ((b * SS + s) * NN + n) * 64 + f];
    ctr[f] = ws[WS_CTX + (l * SS + s) * 64 + f];
    __syncthreads();
    float a = b_out[f];
    for (int q = 0; q < 64; ++q) a = fmaf(ctr[q], ws[WS_WOT + q * 64 + f], a);
    dsr[f] = a;
    __syncthreads();
    float t = b_fa1[f];
    for (int q = 0; q < 64; ++q) t = fmaf(dsr[q], W_fa1[q * 64 + f], t);
    tr[f] = fmaxf(t, 0.f);
    float r = b_rc[f];
    for (int q = 0; q < 64; ++q) r = fmaf(h2r[q], ws[WS_WRCT + q * 64 + f], r);
    __syncthreads();
    float ff = b_fa2[f];
    for (int q = 0; q < 64; ++q) ff = fmaf(tr[q], W_fa2[q * 64 + f], ff);
    comb[s * 64 + f] = r + ff;
    __syncthreads();
  }
  if (f < 12) {
    float o = b_fin[f];
    for (int i = 0; i < 768; ++i) {
      int s = i >> 6, q = i & 63;
      o = fmaf(comb[i], W_fin[(f * SS + s) * 64 + q], o);
    }
    out[(b * SS + f) * NN + n] = o;
  }
}

extern "C" void kernel_launch(void* const* d_in, const int* in_sizes, int n_in,
                              void* d_out, int out_size, void* d_ws, size_t ws_size,
                              hipStream_t stream) {
  (void)in_sizes; (void)n_in; (void)out_size; (void)ws_size;
  const float* x     = (const float*)d_in[0];
  const float* cheb  = (const float*)d_in[1];
  const float* theta = (const float*)d_in[2];
  const float* Wex   = (const float*)d_in[3];
  const float* bex   = (const float*)d_in[4];
  const float* Weos  = (const float*)d_in[5];
  const float* beos  = (const float*)d_in[6];
  const float* U_x   = (const float*)d_in[7];
  const float* V_x   = (const float*)d_in[8];
  const float* b_x   = (const float*)d_in[9];
  const float* U_g   = (const float*)d_in[10];
  const float* V_g   = (const float*)d_in[11];
  const float* b_g   = (const float*)d_in[12];
  const float* W_ff1 = (const float*)d_in[13];
  const float* b_ff1 = (const float*)d_in[14];
  const float* W_ff2 = (const float*)d_in[15];
  const float* b_ff2 = (const float*)d_in[16];
  const float* W_tc  = (const float*)d_in[17];
  const float* b_tc  = (const float*)d_in[18];
  const float* W_rc  = (const float*)d_in[19];
  const float* b_rc  = (const float*)d_in[20];
  const float* W_in  = (const float*)d_in[21];
  const float* b_in  = (const float*)d_in[22];
  const float* W_out = (const float*)d_in[23];
  const float* b_out = (const float*)d_in[24];
  const float* W_fa1 = (const float*)d_in[25];
  const float* b_fa1 = (const float*)d_in[26];
  const float* W_fa2 = (const float*)d_in[27];
  const float* b_fa2 = (const float*)d_in[28];
  const float* W_fin = (const float*)d_in[29];
  const float* b_fin = (const float*)d_in[30];
  float* ws = (float*)d_ws;
  float* outp = (float*)d_out;

  k1_precomp<<<1, 256, 0, stream>>>(theta, Wex, bex, Weos, beos, W_rc, W_out, ws);
  k2_cx<<<144, 320, 0, stream>>>(x, cheb, ws);
  k2c_xfl<<<3684, 256, 0, stream>>>(x, Wex, bex, ws);
  k3_scan<<<1228, 384, 0, stream>>>(U_x, V_x, b_x, U_g, V_g, b_g,
                                    W_ff1, b_ff1, W_ff2, b_ff2, W_tc, b_tc, ws);
  k5_qkv<<<48 * 77, 256, 0, stream>>>(W_in, b_in, ws);
  k6_attn<<<960, 256, 0, stream>>>(ws);
  k7_out<<<1228, 64, 0, stream>>>(W_fa1, b_fa1, W_fa2, b_fa2, b_rc, b_out,
                                  W_fin, b_fin, ws, outp);
}